// Round 1
// 679.695 us; speedup vs baseline: 1.0625x; 1.0625x over previous
//
#include <hip/hip_runtime.h>

#define N_SAMPLES 65536
#define K_CENT    1024
#define DIM       512
// fp16 2-term split: dist error = -2*sum(a*bl), std ~ 2*sqrt(512)*2^-11/sqrt(12) ~ 6.5e-3.
// Flag guarantee needs TAU > 2*eps  ->  0.125 is ~19 sigma. Refine (fp64) fixes flagged.
#define TAU 0.125f

typedef __attribute__((ext_vector_type(8))) short  short8;
typedef _Float16 half8 __attribute__((ext_vector_type(8)));
typedef __attribute__((ext_vector_type(4))) float  float4v;

__device__ inline unsigned short f2h_bits(float x) {   // RTNE fp32 -> fp16 (v_cvt_f16_f32)
    _Float16 h = (_Float16)x;
    return __builtin_bit_cast(unsigned short, h);
}

// ---------------- fused: Bh = fp16(centers), c2[k] = sum(centers[k]^2) ----------------
__global__ __launch_bounds__(256) void hsplit_c2_kernel(const float* __restrict__ cen,
                                                        unsigned short* __restrict__ Bh,
                                                        float* __restrict__ c2) {
    const int k = blockIdx.x, t = threadIdx.x;
    const float* row = cen + (size_t)k * DIM;
    float2 v = ((const float2*)row)[t];
    unsigned int packed = (unsigned)f2h_bits(v.x) | ((unsigned)f2h_bits(v.y) << 16);
    *(unsigned int*)(Bh + (size_t)k * DIM + t * 2) = packed;
    float s = v.x * v.x + v.y * v.y;
    for (int off = 32; off; off >>= 1) s += __shfl_down(s, off);
    __shared__ float w4[4];
    int lane = t & 63, wv = t >> 6;
    if (lane == 0) w4[wv] = s;
    __syncthreads();
    if (t == 0) c2[k] = w4[0] + w4[1] + w4[2] + w4[3];
}

// ---------------- MFMA assign: 128m x 512n per block, fp16 2-term, A direct-to-reg ----------------
__global__ __launch_bounds__(256, 4) void assign_mfma(
    const float* __restrict__ A,            // embedded [N,D] fp32
    const unsigned short* __restrict__ Bh,  // centers fp16 [K,D]
    const float* __restrict__ c2,
    float* __restrict__ pbest,              // [2][65536]
    float* __restrict__ psec,
    int* __restrict__ pidx)
{
    __shared__ __align__(16) unsigned short Bt[4096];   // 8 KB: slot = q*128 + r, 16B/slot
    __shared__ float st_best[128];
    __shared__ float st_sec[128];
    __shared__ int   st_idx[128];

    const int tid  = threadIdx.x;
    const int w    = tid >> 6;        // wave 0..3: rows w*32..w*32+31
    const int lane = tid & 63;
    const int quad = lane >> 4;
    const int l15  = lane & 15;
    const int mblk  = blockIdx.x & 511;
    const int chunk = blockIdx.x >> 9;      // temporal split: chunk0 blocks first -> L2-hot B
    const int m0   = mblk * 128;

    if (tid < 128) { st_best[tid] = 3.4e38f; st_sec[tid] = 3.4e38f; st_idx[tid] = 0; }

    // per-lane A base: row = m0 + w*32 + l15 (+ i*16), col = quad*8 (+ ks*32)
    const float* aBase = A + (size_t)(m0 + w * 32 + l15) * DIM + quad * 8;

    for (int nt = 0; nt < 4; ++nt) {
        const int n0 = chunk * 512 + nt * 128;
        float4v acc[16];
        #pragma unroll
        for (int z = 0; z < 16; ++z) acc[z] = (float4v){0.f, 0.f, 0.f, 0.f};

        for (int ks = 0; ks < 16; ++ks) {
            // ---- A fragment loads straight from global (L2/L3-hot after nt=0);
            //      issued before the barrier so latency hides under barrier-wait ----
            float4 av[2][2];
            #pragma unroll
            for (int i = 0; i < 2; ++i) {
                const float* ap = aBase + i * 16 * DIM + ks * 32;
                av[i][0] = *(const float4*)ap;
                av[i][1] = *(const float4*)(ap + 4);
            }

            __syncthreads();   // previous iteration's Bt readers done
            // ---- stage B tile 128n x 32k (fp16 hi only) into LDS, quad-major slots ----
            #pragma unroll
            for (int i = 0; i < 2; ++i) {
                int s = i * 256 + tid;             // slot 0..511
                int qq = s >> 7, r = s & 127;
                *(short8*)&Bt[s * 8] =
                    *(const short8*)(Bh + (size_t)(n0 + r) * DIM + ks * 32 + qq * 8);
            }
            __syncthreads();   // Bt ready

            // ---- convert A to fp16 hi/lo in registers ----
            half8 ah[2], al[2];
            #pragma unroll
            for (int i = 0; i < 2; ++i) {
                float f[8] = {av[i][0].x, av[i][0].y, av[i][0].z, av[i][0].w,
                              av[i][1].x, av[i][1].y, av[i][1].z, av[i][1].w};
                #pragma unroll
                for (int e = 0; e < 8; ++e) {
                    _Float16 h = (_Float16)f[e];
                    ah[i][e] = h;
                    al[i][e] = (_Float16)(f[e] - (float)h);   // exact residual, fp16-rounded
                }
            }

            // ---- B fragments from LDS; 2-term MFMA: (ah+al)*bh = a*bh ----
            #pragma unroll
            for (int j4 = 0; j4 < 8; ++j4) {
                short8 braw = *(const short8*)&Bt[(quad * 128 + j4 * 16 + l15) * 8];
                half8 bh = __builtin_bit_cast(half8, braw);
                #pragma unroll
                for (int i = 0; i < 2; ++i) {
                    acc[i * 8 + j4] = __builtin_amdgcn_mfma_f32_16x16x32_f16(
                        ah[i], bh, acc[i * 8 + j4], 0, 0, 0);
                    acc[i * 8 + j4] = __builtin_amdgcn_mfma_f32_16x16x32_f16(
                        al[i], bh, acc[i * 8 + j4], 0, 0, 0);
                }
            }
        }

        // epilogue: dist = c2[n] - 2*cross; per-lane best over j, butterfly over l15
        float c2v[8];
        #pragma unroll
        for (int j = 0; j < 8; ++j) c2v[j] = c2[n0 + j * 16 + l15];
        #pragma unroll
        for (int i = 0; i < 2; ++i)
            #pragma unroll
            for (int reg = 0; reg < 4; ++reg) {
                float bv = 3.4e38f, sv = 3.4e38f; int bi = 0;
                #pragma unroll
                for (int j = 0; j < 8; ++j) {
                    float v = c2v[j] - 2.0f * acc[i * 8 + j][reg];
                    int n = n0 + j * 16 + l15;
                    if (v < bv) { sv = bv; bv = v; bi = n; }
                    else if (v < sv) sv = v;
                }
                #pragma unroll
                for (int mask = 1; mask < 16; mask <<= 1) {
                    float ob = __shfl_xor(bv, mask);
                    float os = __shfl_xor(sv, mask);
                    int   oi = __shfl_xor(bi, mask);
                    float ns = fminf(fminf(sv, os), fmaxf(bv, ob));
                    if (ob < bv || (ob == bv && oi < bi)) { bv = ob; bi = oi; }
                    sv = ns;
                }
                if (l15 == 0) {   // unique writer per m
                    int ml = w * 32 + i * 16 + quad * 4 + reg;
                    float sb = st_best[ml], ss = st_sec[ml]; int si = st_idx[ml];
                    float ns = fminf(fminf(ss, sv), fmaxf(sb, bv));
                    if (bv < sb || (bv == sb && bi < si)) { st_best[ml] = bv; st_idx[ml] = bi; }
                    st_sec[ml] = ns;
                }
            }
    }

    __syncthreads();
    if (tid < 128) {
        int m = m0 + tid;
        pbest[chunk * N_SAMPLES + m] = st_best[tid];
        psec [chunk * N_SAMPLES + m] = st_sec[tid];
        pidx [chunk * N_SAMPLES + m] = st_idx[tid];
    }
}

// ---------------- merge the 2 n-chunk partials: s, hist, loss, tie flags ----------------
__global__ __launch_bounds__(256) void merge_kernel(
    const float* __restrict__ pbest,
    const float* __restrict__ psec,
    const int* __restrict__ pidx,
    int* __restrict__ s_idx,
    float* __restrict__ out_s,
    int* __restrict__ hist,
    int* __restrict__ flag_cnt,
    int* __restrict__ flagged,
    float* __restrict__ out_loss)
{
    int m = blockIdx.x * 256 + threadIdx.x;
    float b0 = pbest[m], b1 = pbest[N_SAMPLES + m];
    float s0 = psec[m],  s1 = psec[N_SAMPLES + m];
    int   i0 = pidx[m],  i1 = pidx[N_SAMPLES + m];
    float bv, sv; int bi;
    if (b1 < b0) { bv = b1; bi = i1; sv = fminf(b0, s1); }   // tie -> chunk0 (lower idx)
    else         { bv = b0; bi = i0; sv = fminf(s0, b1); }
    s_idx[m] = bi;
    out_s[m] = (float)bi;
    atomicAdd(&hist[bi], 1);
    if (sv - bv < TAU) { int p = atomicAdd(flag_cnt, 1); flagged[p] = m; }

    float ls = bv;
    for (int off = 32; off; off >>= 1) ls += __shfl_down(ls, off);
    __shared__ float ws4[4];
    int lane = threadIdx.x & 63, wv = threadIdx.x >> 6;
    if (lane == 0) ws4[wv] = ls;
    __syncthreads();
    if (threadIdx.x == 0)
        atomicAdd(out_loss, (ws4[0] + ws4[1] + ws4[2] + ws4[3]) * (1.0f / N_SAMPLES));
}

// ---------------- exact fp64 re-check of flagged near-tie samples (+hist fixup) ----------------
__global__ __launch_bounds__(256) void refine_kernel(
    const float* __restrict__ emb,
    const float* __restrict__ cen,
    const int* __restrict__ flag_cnt,
    const int* __restrict__ flagged,
    int* __restrict__ s_idx,
    float* __restrict__ out_s,
    int* __restrict__ hist)
{
    __shared__ float e_sh[DIM];
    __shared__ double rvd[256];
    __shared__ int rid[256];
    const int t = threadIdx.x;
    const int cnt = *flag_cnt;
    for (int idx = blockIdx.x; idx < cnt; idx += gridDim.x) {
        int n = flagged[idx];
        __syncthreads();
        ((float2*)e_sh)[t] = ((const float2*)(emb + (size_t)n * DIM))[t];
        __syncthreads();
        double bestd = 1e300;
        int bestk = 0;
        #pragma unroll
        for (int j = 0; j < 4; ++j) {
            int k = t * 4 + j;
            const float* crow = cen + (size_t)k * DIM;
            double acc = 0.0;
            for (int d = 0; d < DIM; d += 4) {
                float4 cv = *(const float4*)(crow + d);
                double d0 = (double)e_sh[d + 0] - (double)cv.x;
                double d1 = (double)e_sh[d + 1] - (double)cv.y;
                double d2 = (double)e_sh[d + 2] - (double)cv.z;
                double d3 = (double)e_sh[d + 3] - (double)cv.w;
                acc += d0 * d0 + d1 * d1 + d2 * d2 + d3 * d3;
            }
            if (acc < bestd) { bestd = acc; bestk = k; }
        }
        rvd[t] = bestd; rid[t] = bestk;
        __syncthreads();
        for (int off = 128; off; off >>= 1) {
            if (t < off) {
                double v = rvd[t + off]; int ii = rid[t + off];
                if (v < rvd[t] || (v == rvd[t] && ii < rid[t])) { rvd[t] = v; rid[t] = ii; }
            }
            __syncthreads();
        }
        if (t == 0) {
            int old = s_idx[n], nw = rid[0];
            if (nw != old) {
                atomicSub(&hist[old], 1);
                atomicAdd(&hist[nw], 1);
                s_idx[n] = nw;
                out_s[n] = (float)nw;
            }
        }
    }
}

// ---------------- prefix sum over histogram ----------------
__global__ void scan_kernel(const int* __restrict__ hist,
                            int* __restrict__ offsets,
                            int* __restrict__ cursor,
                            const int* __restrict__ count_in,
                            float* __restrict__ out_count) {
    __shared__ int sbuf[K_CENT];
    int t = threadIdx.x;
    int v = hist[t];
    sbuf[t] = v;
    __syncthreads();
    for (int off = 1; off < K_CENT; off <<= 1) {
        int x = (t >= off) ? sbuf[t - off] : 0;
        __syncthreads();
        sbuf[t] += x;
        __syncthreads();
    }
    int incl = sbuf[t];
    offsets[t] = incl - v;
    cursor[t]  = incl - v;
    out_count[t] = (float)(count_in[t] + v);
    if (t == K_CENT - 1) offsets[K_CENT] = incl;
}

__global__ void scatter_kernel(const int* __restrict__ s_idx,
                               int* __restrict__ cursor,
                               int* __restrict__ order) {
    int n = blockIdx.x * blockDim.x + threadIdx.x;
    if (n < N_SAMPLES) {
        int pos = atomicAdd(&cursor[s_idx[n]], 1);
        order[pos] = n;
    }
}

// ---------------- balanced partial segment sums (fixed 64-entry slices) ----------------
__global__ __launch_bounds__(256) void gp_kernel(
    const float* __restrict__ emb,
    const int* __restrict__ s_idx,
    const int* __restrict__ order,
    float* __restrict__ accum,
    float* __restrict__ out_loss)
{
    __shared__ int s_n[64], s_c[64];
    const int t = threadIdx.x;
    const int base = blockIdx.x * 64;
    if (t < 64) { int n = order[base + t]; s_n[t] = n; s_c[t] = s_idx[n]; }
    __syncthreads();
    float ax = 0.f, ay = 0.f, ssq = 0.f;
    int cur = s_c[0];
    for (int r = 0; r < 64; ++r) {
        int n = s_n[r], c = s_c[r];
        if (c != cur) {   // uniform branch (shared value)
            atomicAdd(&accum[(size_t)cur * DIM + t * 2], ax);
            atomicAdd(&accum[(size_t)cur * DIM + t * 2 + 1], ay);
            ax = ay = 0.f; cur = c;
        }
        float2 e = *(const float2*)(emb + (size_t)n * DIM + t * 2);
        ax += e.x; ay += e.y;
        ssq += e.x * e.x + e.y * e.y;
    }
    atomicAdd(&accum[(size_t)cur * DIM + t * 2], ax);
    atomicAdd(&accum[(size_t)cur * DIM + t * 2 + 1], ay);

    for (int off = 32; off; off >>= 1) ssq += __shfl_down(ssq, off);
    __shared__ float wsum[4];
    if ((t & 63) == 0) wsum[t >> 6] = ssq;
    __syncthreads();
    if (t == 0)
        atomicAdd(out_loss, (wsum[0] + wsum[1] + wsum[2] + wsum[3]) * (1.0f / N_SAMPLES));
}

// ---------------- combine: out_centers = (cnt*c + accum) / (cnt + hist) ----------------
__global__ __launch_bounds__(256) void combine_kernel(
    const float* __restrict__ centers,
    const int* __restrict__ count_in,
    const int* __restrict__ hist,
    const float* __restrict__ accum,
    float* __restrict__ out_centers)
{
    int k = blockIdx.x, t = threadIdx.x;
    float cn = (float)count_in[k];
    float tot = cn + (float)hist[k];
    float2 c = *(const float2*)(centers + (size_t)k * DIM + t * 2);
    float2 a = *(const float2*)(accum   + (size_t)k * DIM + t * 2);
    float2 o;
    o.x = (cn * c.x + a.x) / tot;
    o.y = (cn * c.y + a.y) / tot;
    *(float2*)(out_centers + (size_t)k * DIM + t * 2) = o;
}

extern "C" void kernel_launch(void* const* d_in, const int* in_sizes, int n_in,
                              void* d_out, int out_size, void* d_ws, size_t ws_size,
                              hipStream_t stream) {
    const float* emb = (const float*)d_in[0];
    const float* cen = (const float*)d_in[1];
    const int*   cnt = (const int*)d_in[2];

    float* out = (float*)d_out;
    float* out_loss    = out;
    float* out_s       = out + 1;
    float* out_centers = out + 1 + N_SAMPLES;
    float* out_count   = out + 1 + N_SAMPLES + (size_t)K_CENT * DIM;

    int* wsi = (int*)d_ws;
    int*   hist     = wsi;                       // [0, 1024)
    int*   offsets  = wsi + 1024;                // [1024, 2049) +pad
    int*   cursor   = wsi + 2064;                // [2064, 3088)
    int*   s_idx    = wsi + 4096;                // [4096, 69632)
    float* c2       = (float*)(wsi + 69632);     // [69632, 70656)
    int*   flag_cnt = wsi + 70656;               // [70656, 70720) padded
    int*   flagged  = wsi + 70720;               // [70720, 136256)
    float* pbest    = (float*)(wsi + 136256);    // [136256, 267328)  2 x 65536
    float* psec     = (float*)(wsi + 267328);    // [267328, 398400)
    int*   pidx     = wsi + 398400;              // [398400, 529472)
    unsigned short* Bh = (unsigned short*)(wsi + 529472);  // [529472, 791616) fp16 centers
    // aliases (lifetimes disjoint):
    int*   order    = wsi + 136256;              // aliases pbest (dead after merge)
    float* accum    = (float*)(wsi + 529472);    // aliases Bh+ (dead after assign)

    hipMemsetAsync(hist, 0, K_CENT * sizeof(int), stream);
    hipMemsetAsync(out_loss, 0, sizeof(float), stream);
    hipMemsetAsync(flag_cnt, 0, sizeof(int), stream);

    hsplit_c2_kernel<<<K_CENT, 256, 0, stream>>>(cen, Bh, c2);
    assign_mfma<<<1024, 256, 0, stream>>>(emb, Bh, c2, pbest, psec, pidx);
    merge_kernel<<<N_SAMPLES / 256, 256, 0, stream>>>(pbest, psec, pidx, s_idx, out_s,
                                                      hist, flag_cnt, flagged, out_loss);
    // Bh dead; reuse region as accumulation buffer
    hipMemsetAsync(accum, 0, (size_t)K_CENT * DIM * sizeof(float), stream);
    refine_kernel<<<256, 256, 0, stream>>>(emb, cen, flag_cnt, flagged, s_idx, out_s, hist);
    scan_kernel<<<1, K_CENT, 0, stream>>>(hist, offsets, cursor, cnt, out_count);
    scatter_kernel<<<N_SAMPLES / 256, 256, 0, stream>>>(s_idx, cursor, order);
    gp_kernel<<<N_SAMPLES / 64, 256, 0, stream>>>(emb, s_idx, order, accum, out_loss);
    combine_kernel<<<K_CENT, 256, 0, stream>>>(cen, cnt, hist, accum, out_centers);
}

// Round 2
// 661.233 us; speedup vs baseline: 1.0921x; 1.0279x over previous
//
#include <hip/hip_runtime.h>

#define N_SAMPLES 65536
#define K_CENT    1024
#define DIM       512
// fp16 2-term split: dist error = -2*sum(a*bl), std ~ 2*sqrt(512)*2^-11/sqrt(12) ~ 6.5e-3.
// Flag guarantee needs TAU > 2*eps  ->  0.125 is >13 sigma. Refine (fp64) fixes flagged.
#define TAU 0.125f

typedef __attribute__((ext_vector_type(8))) short  short8;
typedef _Float16 half8 __attribute__((ext_vector_type(8)));
typedef __attribute__((ext_vector_type(4))) float  float4v;

__device__ inline unsigned short f2h_bits(float x) {   // RTNE fp32 -> fp16 (v_cvt_f16_f32)
    _Float16 h = (_Float16)x;
    return __builtin_bit_cast(unsigned short, h);
}

// direct global -> LDS, 16 bytes per lane (wave-uniform LDS base + lane*16)
#define GLD16(gsrc, ldst)                                                        \
    __builtin_amdgcn_global_load_lds(                                            \
        (const __attribute__((address_space(1))) unsigned int*)(gsrc),           \
        (__attribute__((address_space(3))) unsigned int*)(ldst), 16, 0, 0)

// ---------------- fused: Bh = fp16(centers), c2[k] = sum(centers[k]^2) ----------------
__global__ __launch_bounds__(256) void hsplit_c2_kernel(const float* __restrict__ cen,
                                                        unsigned short* __restrict__ Bh,
                                                        float* __restrict__ c2) {
    const int k = blockIdx.x, t = threadIdx.x;
    const float* row = cen + (size_t)k * DIM;
    float2 v = ((const float2*)row)[t];
    unsigned int packed = (unsigned)f2h_bits(v.x) | ((unsigned)f2h_bits(v.y) << 16);
    *(unsigned int*)(Bh + (size_t)k * DIM + t * 2) = packed;
    float s = v.x * v.x + v.y * v.y;
    for (int off = 32; off; off >>= 1) s += __shfl_down(s, off);
    __shared__ float w4[4];
    int lane = t & 63, wv = t >> 6;
    if (lane == 0) w4[wv] = s;
    __syncthreads();
    if (t == 0) c2[k] = w4[0] + w4[1] + w4[2] + w4[3];
}

__device__ inline void loadA(const float* aBase, int kc, float4 av[2][2]) {
    #pragma unroll
    for (int i = 0; i < 2; ++i) {
        const float* ap = aBase + i * 16 * DIM + kc;
        av[i][0] = *(const float4*)ap;
        av[i][1] = *(const float4*)(ap + 4);
    }
}

__device__ inline void cvtA(const float4 av[2][2], half8 ah[2], half8 al[2]) {
    #pragma unroll
    for (int i = 0; i < 2; ++i) {
        float f[8] = {av[i][0].x, av[i][0].y, av[i][0].z, av[i][0].w,
                      av[i][1].x, av[i][1].y, av[i][1].z, av[i][1].w};
        #pragma unroll
        for (int e = 0; e < 8; ++e) {
            _Float16 h = (_Float16)f[e];
            ah[i][e] = h;
            al[i][e] = (_Float16)(f[e] - (float)h);   // exact residual, fp16-rounded
        }
    }
}

// ---------------- MFMA assign: 128m x 512n per block, fp16 2-term ----------------
// Pipelined: 1 barrier per K-step; B via global_load_lds (double-buffered);
// A raw-prefetched at step top, converted at step end (latency under MFMA phase).
__global__ __launch_bounds__(256, 4) void assign_mfma(
    const float* __restrict__ A,            // embedded [N,D] fp32
    const unsigned short* __restrict__ Bh,  // centers fp16 [K,D]
    const float* __restrict__ c2,
    float* __restrict__ pbest,              // [2][65536]
    float* __restrict__ psec,
    int* __restrict__ pidx)
{
    __shared__ __align__(16) unsigned short Bt[2][4096];   // 2 x 8 KB double buffer
    __shared__ float st_best[128];
    __shared__ float st_sec[128];
    __shared__ int   st_idx[128];

    const int tid  = threadIdx.x;
    const int w    = tid >> 6;        // wave 0..3: rows w*32..w*32+31
    const int lane = tid & 63;
    const int quad = lane >> 4;
    const int l15  = lane & 15;
    const int mblk  = blockIdx.x & 511;
    const int chunk = blockIdx.x >> 9;
    const int m0   = mblk * 128;

    if (tid < 128) { st_best[tid] = 3.4e38f; st_sec[tid] = 3.4e38f; st_idx[tid] = 0; }

    // per-lane A base: row = m0 + w*32 + l15 (+ i*16), col = quad*8 (+ ks*32)
    const float* aBase = A + (size_t)(m0 + w * 32 + l15) * DIM + quad * 8;

    // B staging: thread owns slots s0,s1; LDS dst byte = slot*16 (linear in tid)
    const int s0 = tid, s1 = 256 + tid;
    const unsigned short* bsrc0 = Bh + (size_t)(s0 & 127) * DIM + ((s0 >> 7) * 8);
    const unsigned short* bsrc1 = Bh + (size_t)(s1 & 127) * DIM + ((s1 >> 7) * 8);

    for (int nt = 0; nt < 4; ++nt) {
        const int n0 = chunk * 512 + nt * 128;
        const size_t nOff = (size_t)n0 * DIM;
        float4v acc[16];
        #pragma unroll
        for (int z = 0; z < 16; ++z) acc[z] = (float4v){0.f, 0.f, 0.f, 0.f};

        // ---- prologue: stage B(0), load+convert A(0) ----
        GLD16(bsrc0 + nOff, &Bt[0][s0 * 8]);
        GLD16(bsrc1 + nOff, &Bt[0][s1 * 8]);
        float4 avN[2][2];
        half8 ahC[2], alC[2];
        loadA(aBase, 0, avN);
        cvtA(avN, ahC, alC);

        for (int ks = 0; ks < 16; ++ks) {
            // barrier: all waves' B(ks) landed in LDS (own vmcnt drained by compiler),
            // and all waves done reading buf^1 -> safe to overwrite with B(ks+1)
            __syncthreads();
            if (ks < 15) {
                const int kc = (ks + 1) * 32;
                GLD16(bsrc0 + nOff + kc, &Bt[(ks + 1) & 1][s0 * 8]);
                GLD16(bsrc1 + nOff + kc, &Bt[(ks + 1) & 1][s1 * 8]);
                loadA(aBase, kc, avN);          // raw A(ks+1) in flight during MFMAs
            }

            // ---- B fragments from LDS buf[ks&1]; 2-term MFMA: (ah+al)*bh = a*bh ----
            const unsigned short* bb = Bt[ks & 1];
            #pragma unroll
            for (int j4 = 0; j4 < 8; ++j4) {
                short8 braw = *(const short8*)&bb[(quad * 128 + j4 * 16 + l15) * 8];
                half8 bh = __builtin_bit_cast(half8, braw);
                #pragma unroll
                for (int i = 0; i < 2; ++i) {
                    acc[i * 8 + j4] = __builtin_amdgcn_mfma_f32_16x16x32_f16(
                        ahC[i], bh, acc[i * 8 + j4], 0, 0, 0);
                    acc[i * 8 + j4] = __builtin_amdgcn_mfma_f32_16x16x32_f16(
                        alC[i], bh, acc[i * 8 + j4], 0, 0, 0);
                }
            }

            // ---- convert A(ks+1) now that its latency hid under the MFMA phase ----
            if (ks < 15) cvtA(avN, ahC, alC);
        }

        // epilogue: dist = c2[n] - 2*cross; per-lane best over j, butterfly over l15
        float c2v[8];
        #pragma unroll
        for (int j = 0; j < 8; ++j) c2v[j] = c2[n0 + j * 16 + l15];
        #pragma unroll
        for (int i = 0; i < 2; ++i)
            #pragma unroll
            for (int reg = 0; reg < 4; ++reg) {
                float bv = 3.4e38f, sv = 3.4e38f; int bi = 0;
                #pragma unroll
                for (int j = 0; j < 8; ++j) {
                    float v = c2v[j] - 2.0f * acc[i * 8 + j][reg];
                    int n = n0 + j * 16 + l15;
                    if (v < bv) { sv = bv; bv = v; bi = n; }
                    else if (v < sv) sv = v;
                }
                #pragma unroll
                for (int mask = 1; mask < 16; mask <<= 1) {
                    float ob = __shfl_xor(bv, mask);
                    float os = __shfl_xor(sv, mask);
                    int   oi = __shfl_xor(bi, mask);
                    float ns = fminf(fminf(sv, os), fmaxf(bv, ob));
                    if (ob < bv || (ob == bv && oi < bi)) { bv = ob; bi = oi; }
                    sv = ns;
                }
                if (l15 == 0) {   // unique writer per m
                    int ml = w * 32 + i * 16 + quad * 4 + reg;
                    float sb = st_best[ml], ss = st_sec[ml]; int si = st_idx[ml];
                    float ns = fminf(fminf(ss, sv), fmaxf(sb, bv));
                    if (bv < sb || (bv == sb && bi < si)) { st_best[ml] = bv; st_idx[ml] = bi; }
                    st_sec[ml] = ns;
                }
            }
    }

    __syncthreads();
    if (tid < 128) {
        int m = m0 + tid;
        pbest[chunk * N_SAMPLES + m] = st_best[tid];
        psec [chunk * N_SAMPLES + m] = st_sec[tid];
        pidx [chunk * N_SAMPLES + m] = st_idx[tid];
    }
}

// ---------------- merge the 2 n-chunk partials: s, hist, loss, tie flags ----------------
__global__ __launch_bounds__(256) void merge_kernel(
    const float* __restrict__ pbest,
    const float* __restrict__ psec,
    const int* __restrict__ pidx,
    int* __restrict__ s_idx,
    float* __restrict__ out_s,
    int* __restrict__ hist,
    int* __restrict__ flag_cnt,
    int* __restrict__ flagged,
    float* __restrict__ out_loss)
{
    int m = blockIdx.x * 256 + threadIdx.x;
    float b0 = pbest[m], b1 = pbest[N_SAMPLES + m];
    float s0 = psec[m],  s1 = psec[N_SAMPLES + m];
    int   i0 = pidx[m],  i1 = pidx[N_SAMPLES + m];
    float bv, sv; int bi;
    if (b1 < b0) { bv = b1; bi = i1; sv = fminf(b0, s1); }   // tie -> chunk0 (lower idx)
    else         { bv = b0; bi = i0; sv = fminf(s0, b1); }
    s_idx[m] = bi;
    out_s[m] = (float)bi;
    atomicAdd(&hist[bi], 1);
    if (sv - bv < TAU) { int p = atomicAdd(flag_cnt, 1); flagged[p] = m; }

    float ls = bv;
    for (int off = 32; off; off >>= 1) ls += __shfl_down(ls, off);
    __shared__ float ws4[4];
    int lane = threadIdx.x & 63, wv = threadIdx.x >> 6;
    if (lane == 0) ws4[wv] = ls;
    __syncthreads();
    if (threadIdx.x == 0)
        atomicAdd(out_loss, (ws4[0] + ws4[1] + ws4[2] + ws4[3]) * (1.0f / N_SAMPLES));
}

// ---------------- exact fp64 re-check of flagged near-tie samples (+hist fixup) ----------------
__global__ __launch_bounds__(256) void refine_kernel(
    const float* __restrict__ emb,
    const float* __restrict__ cen,
    const int* __restrict__ flag_cnt,
    const int* __restrict__ flagged,
    int* __restrict__ s_idx,
    float* __restrict__ out_s,
    int* __restrict__ hist)
{
    __shared__ float e_sh[DIM];
    __shared__ double rvd[256];
    __shared__ int rid[256];
    const int t = threadIdx.x;
    const int cnt = *flag_cnt;
    for (int idx = blockIdx.x; idx < cnt; idx += gridDim.x) {
        int n = flagged[idx];
        __syncthreads();
        ((float2*)e_sh)[t] = ((const float2*)(emb + (size_t)n * DIM))[t];
        __syncthreads();
        double bestd = 1e300;
        int bestk = 0;
        #pragma unroll
        for (int j = 0; j < 4; ++j) {
            int k = t * 4 + j;
            const float* crow = cen + (size_t)k * DIM;
            double acc = 0.0;
            for (int d = 0; d < DIM; d += 4) {
                float4 cv = *(const float4*)(crow + d);
                double d0 = (double)e_sh[d + 0] - (double)cv.x;
                double d1 = (double)e_sh[d + 1] - (double)cv.y;
                double d2 = (double)e_sh[d + 2] - (double)cv.z;
                double d3 = (double)e_sh[d + 3] - (double)cv.w;
                acc += d0 * d0 + d1 * d1 + d2 * d2 + d3 * d3;
            }
            if (acc < bestd) { bestd = acc; bestk = k; }
        }
        rvd[t] = bestd; rid[t] = bestk;
        __syncthreads();
        for (int off = 128; off; off >>= 1) {
            if (t < off) {
                double v = rvd[t + off]; int ii = rid[t + off];
                if (v < rvd[t] || (v == rvd[t] && ii < rid[t])) { rvd[t] = v; rid[t] = ii; }
            }
            __syncthreads();
        }
        if (t == 0) {
            int old = s_idx[n], nw = rid[0];
            if (nw != old) {
                atomicSub(&hist[old], 1);
                atomicAdd(&hist[nw], 1);
                s_idx[n] = nw;
                out_s[n] = (float)nw;
            }
        }
    }
}

// ---------------- prefix sum over histogram ----------------
__global__ void scan_kernel(const int* __restrict__ hist,
                            int* __restrict__ offsets,
                            int* __restrict__ cursor,
                            const int* __restrict__ count_in,
                            float* __restrict__ out_count) {
    __shared__ int sbuf[K_CENT];
    int t = threadIdx.x;
    int v = hist[t];
    sbuf[t] = v;
    __syncthreads();
    for (int off = 1; off < K_CENT; off <<= 1) {
        int x = (t >= off) ? sbuf[t - off] : 0;
        __syncthreads();
        sbuf[t] += x;
        __syncthreads();
    }
    int incl = sbuf[t];
    offsets[t] = incl - v;
    cursor[t]  = incl - v;
    out_count[t] = (float)(count_in[t] + v);
    if (t == K_CENT - 1) offsets[K_CENT] = incl;
}

__global__ void scatter_kernel(const int* __restrict__ s_idx,
                               int* __restrict__ cursor,
                               int* __restrict__ order) {
    int n = blockIdx.x * blockDim.x + threadIdx.x;
    if (n < N_SAMPLES) {
        int pos = atomicAdd(&cursor[s_idx[n]], 1);
        order[pos] = n;
    }
}

// ---------------- balanced partial segment sums (fixed 64-entry slices) ----------------
__global__ __launch_bounds__(256) void gp_kernel(
    const float* __restrict__ emb,
    const int* __restrict__ s_idx,
    const int* __restrict__ order,
    float* __restrict__ accum,
    float* __restrict__ out_loss)
{
    __shared__ int s_n[64], s_c[64];
    const int t = threadIdx.x;
    const int base = blockIdx.x * 64;
    if (t < 64) { int n = order[base + t]; s_n[t] = n; s_c[t] = s_idx[n]; }
    __syncthreads();
    float ax = 0.f, ay = 0.f, ssq = 0.f;
    int cur = s_c[0];
    for (int r = 0; r < 64; ++r) {
        int n = s_n[r], c = s_c[r];
        if (c != cur) {   // uniform branch (shared value)
            atomicAdd(&accum[(size_t)cur * DIM + t * 2], ax);
            atomicAdd(&accum[(size_t)cur * DIM + t * 2 + 1], ay);
            ax = ay = 0.f; cur = c;
        }
        float2 e = *(const float2*)(emb + (size_t)n * DIM + t * 2);
        ax += e.x; ay += e.y;
        ssq += e.x * e.x + e.y * e.y;
    }
    atomicAdd(&accum[(size_t)cur * DIM + t * 2], ax);
    atomicAdd(&accum[(size_t)cur * DIM + t * 2 + 1], ay);

    for (int off = 32; off; off >>= 1) ssq += __shfl_down(ssq, off);
    __shared__ float wsum[4];
    if ((t & 63) == 0) wsum[t >> 6] = ssq;
    __syncthreads();
    if (t == 0)
        atomicAdd(out_loss, (wsum[0] + wsum[1] + wsum[2] + wsum[3]) * (1.0f / N_SAMPLES));
}

// ---------------- combine: out_centers = (cnt*c + accum) / (cnt + hist) ----------------
__global__ __launch_bounds__(256) void combine_kernel(
    const float* __restrict__ centers,
    const int* __restrict__ count_in,
    const int* __restrict__ hist,
    const float* __restrict__ accum,
    float* __restrict__ out_centers)
{
    int k = blockIdx.x, t = threadIdx.x;
    float cn = (float)count_in[k];
    float tot = cn + (float)hist[k];
    float2 c = *(const float2*)(centers + (size_t)k * DIM + t * 2);
    float2 a = *(const float2*)(accum   + (size_t)k * DIM + t * 2);
    float2 o;
    o.x = (cn * c.x + a.x) / tot;
    o.y = (cn * c.y + a.y) / tot;
    *(float2*)(out_centers + (size_t)k * DIM + t * 2) = o;
}

extern "C" void kernel_launch(void* const* d_in, const int* in_sizes, int n_in,
                              void* d_out, int out_size, void* d_ws, size_t ws_size,
                              hipStream_t stream) {
    const float* emb = (const float*)d_in[0];
    const float* cen = (const float*)d_in[1];
    const int*   cnt = (const int*)d_in[2];

    float* out = (float*)d_out;
    float* out_loss    = out;
    float* out_s       = out + 1;
    float* out_centers = out + 1 + N_SAMPLES;
    float* out_count   = out + 1 + N_SAMPLES + (size_t)K_CENT * DIM;

    int* wsi = (int*)d_ws;
    int*   hist     = wsi;                       // [0, 1024)
    int*   offsets  = wsi + 1024;                // [1024, 2049) +pad
    int*   cursor   = wsi + 2064;                // [2064, 3088)
    int*   s_idx    = wsi + 4096;                // [4096, 69632)
    float* c2       = (float*)(wsi + 69632);     // [69632, 70656)
    int*   flag_cnt = wsi + 70656;               // [70656, 70720) padded
    int*   flagged  = wsi + 70720;               // [70720, 136256)
    float* pbest    = (float*)(wsi + 136256);    // [136256, 267328)  2 x 65536
    float* psec     = (float*)(wsi + 267328);    // [267328, 398400)
    int*   pidx     = wsi + 398400;              // [398400, 529472)
    unsigned short* Bh = (unsigned short*)(wsi + 529472);  // [529472, 791616) fp16 centers
    // aliases (lifetimes disjoint):
    int*   order    = wsi + 136256;              // aliases pbest (dead after merge)
    float* accum    = (float*)(wsi + 529472);    // aliases Bh+ (dead after assign)

    hipMemsetAsync(hist, 0, K_CENT * sizeof(int), stream);
    hipMemsetAsync(out_loss, 0, sizeof(float), stream);
    hipMemsetAsync(flag_cnt, 0, sizeof(int), stream);

    hsplit_c2_kernel<<<K_CENT, 256, 0, stream>>>(cen, Bh, c2);
    assign_mfma<<<1024, 256, 0, stream>>>(emb, Bh, c2, pbest, psec, pidx);
    merge_kernel<<<N_SAMPLES / 256, 256, 0, stream>>>(pbest, psec, pidx, s_idx, out_s,
                                                      hist, flag_cnt, flagged, out_loss);
    // Bh dead; reuse region as accumulation buffer
    hipMemsetAsync(accum, 0, (size_t)K_CENT * DIM * sizeof(float), stream);
    refine_kernel<<<256, 256, 0, stream>>>(emb, cen, flag_cnt, flagged, s_idx, out_s, hist);
    scan_kernel<<<1, K_CENT, 0, stream>>>(hist, offsets, cursor, cnt, out_count);
    scatter_kernel<<<N_SAMPLES / 256, 256, 0, stream>>>(s_idx, cursor, order);
    gp_kernel<<<N_SAMPLES / 64, 256, 0, stream>>>(emb, s_idx, order, accum, out_loss);
    combine_kernel<<<K_CENT, 256, 0, stream>>>(cen, cnt, hist, accum, out_centers);
}

// Round 5
// 652.250 us; speedup vs baseline: 1.1072x; 1.0138x over previous
//
#include <hip/hip_runtime.h>

#define N_SAMPLES 65536
#define K_CENT    1024
#define DIM       512
// fp16 2-term split: dist error = -2*sum(a*bl), sigma ~ 6.5e-3; diff of two ~9.2e-3.
// TAU = 0.125 ~ 13.6 sigma (round-2-verified margin); fp64 refine fixes flagged ties.
#define TAU 0.125f

typedef __attribute__((ext_vector_type(8))) short  short8;
typedef _Float16 half8 __attribute__((ext_vector_type(8)));
typedef __attribute__((ext_vector_type(4))) float  float4v;

__device__ inline unsigned short f2h_bits(float x) {
    _Float16 h = (_Float16)x;
    return __builtin_bit_cast(unsigned short, h);
}

// ---------------- pack: Bp = fp16 centers in fragment-slot order, + c2 ----------------
// Bp slot s (16B): s = (ntG*16+kk)*512 + j4*64 + quad*16 + l15
//   content = centers[ntG*128 + j4*16 + l15][kk*32 + quad*8 .. +8] as fp16
// so assign's per-j4 B load is base + lane*16 : perfectly coalesced.
__global__ __launch_bounds__(256) void pack_kernel(const float* __restrict__ cen,
                                                   unsigned short* __restrict__ Bp,
                                                   float* __restrict__ c2) {
    const int wv = threadIdx.x >> 6, lane = threadIdx.x & 63;
    const int k = blockIdx.x * 4 + wv;          // center row 0..1023
    const int kk = lane >> 2, quad = lane & 3;  // 16 kk x 4 quad = 64 lanes
    const float* src = cen + (size_t)k * DIM + kk * 32 + quad * 8;
    float4 v0 = *(const float4*)src;
    float4 v1 = *(const float4*)(src + 4);
    float f[8] = {v0.x, v0.y, v0.z, v0.w, v1.x, v1.y, v1.z, v1.w};
    short8 h;
    float s = 0.f;
    #pragma unroll
    for (int e = 0; e < 8; ++e) { h[e] = (short)f2h_bits(f[e]); s += f[e] * f[e]; }
    const int ntG = k >> 7, j4 = (k >> 4) & 7, l15 = k & 15;
    size_t slot = (size_t)(ntG * 16 + kk) * 512 + j4 * 64 + quad * 16 + l15;
    *(short8*)(Bp + slot * 8) = h;
    for (int off = 32; off; off >>= 1) s += __shfl_down(s, off);
    if (lane == 0) c2[k] = s;
}

__device__ inline void loadA(const float* aBase, int kc, float4 av[2][2]) {
    #pragma unroll
    for (int i = 0; i < 2; ++i) {
        const float* ap = aBase + (size_t)i * 16 * DIM + kc;
        av[i][0] = *(const float4*)ap;
        av[i][1] = *(const float4*)(ap + 4);
    }
}

__device__ inline void cvtA(const float4 av[2][2], half8 ah[2], half8 al[2]) {
    #pragma unroll
    for (int i = 0; i < 2; ++i) {
        float f[8] = {av[i][0].x, av[i][0].y, av[i][0].z, av[i][0].w,
                      av[i][1].x, av[i][1].y, av[i][1].z, av[i][1].w};
        #pragma unroll
        for (int e = 0; e < 8; ++e) {
            _Float16 h = (_Float16)f[e];
            ah[i][e] = h;
            al[i][e] = (_Float16)(f[e] - (float)h);   // exact residual, fp16-rounded
        }
    }
}

// ---------------- MFMA assign: 128m x 512n per block, fp16 2-term ----------------
// No LDS and no __syncthreads in the K loop. B fragments loaded coalesced from
// packed Bp (L2-resident) direct to registers; A fragments loaded per-lane from
// global (sector-friendly), prefetched 1 K-step ahead, converted under the MFMAs.
__global__ __launch_bounds__(256, 4) void assign_mfma(
    const float* __restrict__ A,            // embedded [N,D] fp32
    const unsigned short* __restrict__ Bp,  // packed fp16 centers (1 MB)
    const float* __restrict__ c2,
    float* __restrict__ pbest,              // [2][65536]
    float* __restrict__ psec,
    int* __restrict__ pidx)
{
    __shared__ float st_best[128];
    __shared__ float st_sec[128];
    __shared__ int   st_idx[128];

    const int tid  = threadIdx.x;
    const int w    = tid >> 6;        // wave 0..3: rows w*32..w*32+31
    const int lane = tid & 63;
    const int quad = lane >> 4;
    const int l15  = lane & 15;
    const int mblk  = blockIdx.x & 511;
    const int chunk = blockIdx.x >> 9;
    const int m0   = mblk * 128;

    if (tid < 128) { st_best[tid] = 3.4e38f; st_sec[tid] = 3.4e38f; st_idx[tid] = 0; }
    __syncthreads();   // init visible before any wave's epilogue updates

    // per-lane A base: row = m0 + w*32 + l15 (+ i*16), col = quad*8 (+ ks*32)
    const float* aBase = A + (size_t)(m0 + w * 32 + l15) * DIM + quad * 8;

    for (int nt = 0; nt < 4; ++nt) {
        const int ntG = chunk * 4 + nt;
        const int n0  = ntG * 128;
        const unsigned short* bBase = Bp + (size_t)ntG * 16 * 4096;  // 16 kk * 512 slots * 8

        float4v acc[16];
        #pragma unroll
        for (int z = 0; z < 16; ++z) acc[z] = (float4v){0.f, 0.f, 0.f, 0.f};

        // prologue: load+convert A(0)
        float4 avN[2][2];
        half8 ah[2], al[2];
        loadA(aBase, 0, avN);
        cvtA(avN, ah, al);

        for (int ks = 0; ks < 16; ++ks) {
            const unsigned short* bk = bBase + (size_t)ks * 4096;

            // B batch 1 (j4 = 0..3), coalesced: 16B/lane, 1KB/wave contiguous
            short8 br0 = *(const short8*)(bk + 0 * 512 + lane * 8);
            short8 br1 = *(const short8*)(bk + 1 * 512 + lane * 8);
            short8 br2 = *(const short8*)(bk + 2 * 512 + lane * 8);
            short8 br3 = *(const short8*)(bk + 3 * 512 + lane * 8);

            // prefetch raw A(ks+1); latency hides under this step's 32 MFMAs
            if (ks < 15) loadA(aBase, (ks + 1) * 32, avN);

            #pragma unroll
            for (int j4 = 0; j4 < 4; ++j4) {
                short8 braw = (j4 == 0) ? br0 : (j4 == 1) ? br1 : (j4 == 2) ? br2 : br3;
                half8 bh = __builtin_bit_cast(half8, braw);
                #pragma unroll
                for (int i = 0; i < 2; ++i) {
                    acc[i * 8 + j4] = __builtin_amdgcn_mfma_f32_16x16x32_f16(
                        ah[i], bh, acc[i * 8 + j4], 0, 0, 0);
                    acc[i * 8 + j4] = __builtin_amdgcn_mfma_f32_16x16x32_f16(
                        al[i], bh, acc[i * 8 + j4], 0, 0, 0);
                }
            }

            // B batch 2 (j4 = 4..7)
            short8 br4 = *(const short8*)(bk + 4 * 512 + lane * 8);
            short8 br5 = *(const short8*)(bk + 5 * 512 + lane * 8);
            short8 br6 = *(const short8*)(bk + 6 * 512 + lane * 8);
            short8 br7 = *(const short8*)(bk + 7 * 512 + lane * 8);
            #pragma unroll
            for (int j4 = 4; j4 < 8; ++j4) {
                short8 braw = (j4 == 4) ? br4 : (j4 == 5) ? br5 : (j4 == 6) ? br6 : br7;
                half8 bh = __builtin_bit_cast(half8, braw);
                #pragma unroll
                for (int i = 0; i < 2; ++i) {
                    acc[i * 8 + j4] = __builtin_amdgcn_mfma_f32_16x16x32_f16(
                        ah[i], bh, acc[i * 8 + j4], 0, 0, 0);
                    acc[i * 8 + j4] = __builtin_amdgcn_mfma_f32_16x16x32_f16(
                        al[i], bh, acc[i * 8 + j4], 0, 0, 0);
                }
            }

            // convert A(ks+1) now that its loads have drained under the MFMAs
            if (ks < 15) cvtA(avN, ah, al);
        }

        // epilogue: dist = c2[n] - 2*cross; per-lane best over j, butterfly over l15
        float c2v[8];
        #pragma unroll
        for (int j = 0; j < 8; ++j) c2v[j] = c2[n0 + j * 16 + l15];
        #pragma unroll
        for (int i = 0; i < 2; ++i)
            #pragma unroll
            for (int reg = 0; reg < 4; ++reg) {
                float bv = 3.4e38f, sv = 3.4e38f; int bi = 0;
                #pragma unroll
                for (int j = 0; j < 8; ++j) {
                    float v = c2v[j] - 2.0f * acc[i * 8 + j][reg];
                    int n = n0 + j * 16 + l15;
                    if (v < bv) { sv = bv; bv = v; bi = n; }
                    else if (v < sv) sv = v;
                }
                #pragma unroll
                for (int mask = 1; mask < 16; mask <<= 1) {
                    float ob = __shfl_xor(bv, mask);
                    float os = __shfl_xor(sv, mask);
                    int   oi = __shfl_xor(bi, mask);
                    float ns = fminf(fminf(sv, os), fmaxf(bv, ob));
                    if (ob < bv || (ob == bv && oi < bi)) { bv = ob; bi = oi; }
                    sv = ns;
                }
                if (l15 == 0) {   // unique writer per m (rows wave-exclusive, no race)
                    int ml = w * 32 + i * 16 + quad * 4 + reg;
                    float sb = st_best[ml], ss = st_sec[ml]; int si = st_idx[ml];
                    float ns = fminf(fminf(ss, sv), fmaxf(sb, bv));
                    if (bv < sb || (bv == sb && bi < si)) { st_best[ml] = bv; st_idx[ml] = bi; }
                    st_sec[ml] = ns;
                }
            }
    }

    __syncthreads();   // st_* ready for linear write-out
    if (tid < 128) {
        int m = m0 + tid;
        pbest[chunk * N_SAMPLES + m] = st_best[tid];
        psec [chunk * N_SAMPLES + m] = st_sec[tid];
        pidx [chunk * N_SAMPLES + m] = st_idx[tid];
    }
}

// ---------------- merge the 2 n-chunk partials: s, hist, loss(f64), tie flags ----------------
__global__ __launch_bounds__(256) void merge_kernel(
    const float* __restrict__ pbest,
    const float* __restrict__ psec,
    const int* __restrict__ pidx,
    int* __restrict__ s_idx,
    float* __restrict__ out_s,
    int* __restrict__ hist,
    int* __restrict__ flag_cnt,
    int* __restrict__ flagged,
    double* __restrict__ loss_d)
{
    int m = blockIdx.x * 256 + threadIdx.x;
    float b0 = pbest[m], b1 = pbest[N_SAMPLES + m];
    float s0 = psec[m],  s1 = psec[N_SAMPLES + m];
    int   i0 = pidx[m],  i1 = pidx[N_SAMPLES + m];
    float bv, sv; int bi;
    if (b1 < b0) { bv = b1; bi = i1; sv = fminf(b0, s1); }   // tie -> chunk0 (lower idx)
    else         { bv = b0; bi = i0; sv = fminf(s0, b1); }
    s_idx[m] = bi;
    out_s[m] = (float)bi;
    atomicAdd(&hist[bi], 1);
    if (sv - bv < TAU) { int p = atomicAdd(flag_cnt, 1); flagged[p] = m; }

    float ls = bv;
    for (int off = 32; off; off >>= 1) ls += __shfl_down(ls, off);
    __shared__ float ws4[4];
    int lane = threadIdx.x & 63, wv = threadIdx.x >> 6;
    if (lane == 0) ws4[wv] = ls;
    __syncthreads();
    if (threadIdx.x == 0)
        atomicAdd(loss_d, (double)(ws4[0] + ws4[1] + ws4[2] + ws4[3]));
}

// ---------------- exact fp64 re-check of flagged near-tie samples (+hist fixup) ----------------
__global__ __launch_bounds__(256) void refine_kernel(
    const float* __restrict__ emb,
    const float* __restrict__ cen,
    const int* __restrict__ flag_cnt,
    const int* __restrict__ flagged,
    int* __restrict__ s_idx,
    float* __restrict__ out_s,
    int* __restrict__ hist)
{
    __shared__ float e_sh[DIM];
    __shared__ double rvd[256];
    __shared__ int rid[256];
    const int t = threadIdx.x;
    const int cnt = *flag_cnt;
    for (int idx = blockIdx.x; idx < cnt; idx += gridDim.x) {
        int n = flagged[idx];
        __syncthreads();
        ((float2*)e_sh)[t] = ((const float2*)(emb + (size_t)n * DIM))[t];
        __syncthreads();
        double bestd = 1e300;
        int bestk = 0;
        #pragma unroll
        for (int j = 0; j < 4; ++j) {
            int k = t * 4 + j;
            const float* crow = cen + (size_t)k * DIM;
            double acc = 0.0;
            for (int d = 0; d < DIM; d += 4) {
                float4 cv = *(const float4*)(crow + d);
                double d0 = (double)e_sh[d + 0] - (double)cv.x;
                double d1 = (double)e_sh[d + 1] - (double)cv.y;
                double d2 = (double)e_sh[d + 2] - (double)cv.z;
                double d3 = (double)e_sh[d + 3] - (double)cv.w;
                acc += d0 * d0 + d1 * d1 + d2 * d2 + d3 * d3;
            }
            if (acc < bestd) { bestd = acc; bestk = k; }
        }
        rvd[t] = bestd; rid[t] = bestk;
        __syncthreads();
        for (int off = 128; off; off >>= 1) {
            if (t < off) {
                double v = rvd[t + off]; int ii = rid[t + off];
                if (v < rvd[t] || (v == rvd[t] && ii < rid[t])) { rvd[t] = v; rid[t] = ii; }
            }
            __syncthreads();
        }
        if (t == 0) {
            int old = s_idx[n], nw = rid[0];
            if (nw != old) {
                atomicSub(&hist[old], 1);
                atomicAdd(&hist[nw], 1);
                s_idx[n] = nw;
                out_s[n] = (float)nw;
            }
        }
    }
}

// ---------------- prefix sum over histogram ----------------
__global__ void scan_kernel(const int* __restrict__ hist,
                            int* __restrict__ offsets,
                            int* __restrict__ cursor,
                            const int* __restrict__ count_in,
                            float* __restrict__ out_count) {
    __shared__ int sbuf[K_CENT];
    int t = threadIdx.x;
    int v = hist[t];
    sbuf[t] = v;
    __syncthreads();
    for (int off = 1; off < K_CENT; off <<= 1) {
        int x = (t >= off) ? sbuf[t - off] : 0;
        __syncthreads();
        sbuf[t] += x;
        __syncthreads();
    }
    int incl = sbuf[t];
    offsets[t] = incl - v;
    cursor[t]  = incl - v;
    out_count[t] = (float)(count_in[t] + v);
    if (t == K_CENT - 1) offsets[K_CENT] = incl;
}

__global__ void scatter_kernel(const int* __restrict__ s_idx,
                               int* __restrict__ cursor,
                               int* __restrict__ order) {
    int n = blockIdx.x * blockDim.x + threadIdx.x;
    if (n < N_SAMPLES) {
        int pos = atomicAdd(&cursor[s_idx[n]], 1);
        order[pos] = n;
    }
}

// ---------------- balanced partial segment sums (fixed 64-entry slices) ----------------
__global__ __launch_bounds__(256) void gp_kernel(
    const float* __restrict__ emb,
    const int* __restrict__ s_idx,
    const int* __restrict__ order,
    float* __restrict__ accum,
    double* __restrict__ loss_d)
{
    __shared__ int s_n[64], s_c[64];
    const int t = threadIdx.x;
    const int base = blockIdx.x * 64;
    if (t < 64) { int n = order[base + t]; s_n[t] = n; s_c[t] = s_idx[n]; }
    __syncthreads();
    float ax = 0.f, ay = 0.f, ssq = 0.f;
    int cur = s_c[0];
    for (int r = 0; r < 64; ++r) {
        int n = s_n[r], c = s_c[r];
        if (c != cur) {   // uniform branch (shared value)
            atomicAdd(&accum[(size_t)cur * DIM + t * 2], ax);
            atomicAdd(&accum[(size_t)cur * DIM + t * 2 + 1], ay);
            ax = ay = 0.f; cur = c;
        }
        float2 e = *(const float2*)(emb + (size_t)n * DIM + t * 2);
        ax += e.x; ay += e.y;
        ssq += e.x * e.x + e.y * e.y;
    }
    atomicAdd(&accum[(size_t)cur * DIM + t * 2], ax);
    atomicAdd(&accum[(size_t)cur * DIM + t * 2 + 1], ay);

    for (int off = 32; off; off >>= 1) ssq += __shfl_down(ssq, off);
    __shared__ float wsum[4];
    if ((t & 63) == 0) wsum[t >> 6] = ssq;
    __syncthreads();
    if (t == 0)
        atomicAdd(loss_d, (double)(wsum[0] + wsum[1] + wsum[2] + wsum[3]));
}

// ---------------- combine: out_centers = (cnt*c + accum) / (cnt + hist); finalize loss ----------------
__global__ __launch_bounds__(256) void combine_kernel(
    const float* __restrict__ centers,
    const int* __restrict__ count_in,
    const int* __restrict__ hist,
    const float* __restrict__ accum,
    const double* __restrict__ loss_d,
    float* __restrict__ out_centers,
    float* __restrict__ out_loss)
{
    int k = blockIdx.x, t = threadIdx.x;
    if (k == 0 && t == 0) *out_loss = (float)(*loss_d * (1.0 / N_SAMPLES));
    float cn = (float)count_in[k];
    float tot = cn + (float)hist[k];
    float2 c = *(const float2*)(centers + (size_t)k * DIM + t * 2);
    float2 a = *(const float2*)(accum   + (size_t)k * DIM + t * 2);
    float2 o;
    o.x = (cn * c.x + a.x) / tot;
    o.y = (cn * c.y + a.y) / tot;
    *(float2*)(out_centers + (size_t)k * DIM + t * 2) = o;
}

extern "C" void kernel_launch(void* const* d_in, const int* in_sizes, int n_in,
                              void* d_out, int out_size, void* d_ws, size_t ws_size,
                              hipStream_t stream) {
    const float* emb = (const float*)d_in[0];
    const float* cen = (const float*)d_in[1];
    const int*   cnt = (const int*)d_in[2];

    float* out = (float*)d_out;
    float* out_loss    = out;
    float* out_s       = out + 1;
    float* out_centers = out + 1 + N_SAMPLES;
    float* out_count   = out + 1 + N_SAMPLES + (size_t)K_CENT * DIM;

    int* wsi = (int*)d_ws;
    int*   hist     = wsi;                       // [0, 1024)
    int*   offsets  = wsi + 1024;                // [1024, 2049) +pad
    int*   cursor   = wsi + 2064;                // [2064, 3088)
    int*   s_idx    = wsi + 4096;                // [4096, 69632)
    float* c2       = (float*)(wsi + 69632);     // [69632, 70656)
    int*   flag_cnt = wsi + 70656;               // 1 int, padded region [70656, 70712)
    double* loss_d  = (double*)(wsi + 70712);    // [70712, 70714) 8B-aligned, no overlap
    int*   flagged  = wsi + 70720;               // [70720, 136256)
    float* pbest    = (float*)(wsi + 136256);    // [136256, 267328)  2 x 65536
    float* psec     = (float*)(wsi + 267328);    // [267328, 398400)
    int*   pidx     = wsi + 398400;              // [398400, 529472)
    unsigned short* Bp = (unsigned short*)(wsi + 529472);  // [529472, 791616) packed fp16
    // aliases (lifetimes disjoint):
    int*   order    = wsi + 136256;              // aliases pbest (dead after merge)
    float* accum    = (float*)(wsi + 529472);    // aliases Bp+ (dead after assign)

    hipMemsetAsync(hist, 0, K_CENT * sizeof(int), stream);
    hipMemsetAsync(loss_d, 0, sizeof(double), stream);
    hipMemsetAsync(flag_cnt, 0, sizeof(int), stream);

    pack_kernel<<<256, 256, 0, stream>>>(cen, Bp, c2);
    assign_mfma<<<1024, 256, 0, stream>>>(emb, Bp, c2, pbest, psec, pidx);
    merge_kernel<<<N_SAMPLES / 256, 256, 0, stream>>>(pbest, psec, pidx, s_idx, out_s,
                                                      hist, flag_cnt, flagged, loss_d);
    // Bp dead; reuse region as accumulation buffer
    hipMemsetAsync(accum, 0, (size_t)K_CENT * DIM * sizeof(float), stream);
    refine_kernel<<<256, 256, 0, stream>>>(emb, cen, flag_cnt, flagged, s_idx, out_s, hist);
    scan_kernel<<<1, K_CENT, 0, stream>>>(hist, offsets, cursor, cnt, out_count);
    scatter_kernel<<<N_SAMPLES / 256, 256, 0, stream>>>(s_idx, cursor, order);
    gp_kernel<<<N_SAMPLES / 64, 256, 0, stream>>>(emb, s_idx, order, accum, loss_d);
    combine_kernel<<<K_CENT, 256, 0, stream>>>(cen, cnt, hist, accum, loss_d,
                                               out_centers, out_loss);
}